// Round 10
// baseline (228.271 us; speedup 1.0000x reference)
//
#include <hip/hip_runtime.h>
#include <cstdint>

// BinConv2dEval: y = conv3x3(x,W) + bias; out = (sign*y >= 0) ? 1 : 0
// x: [32][128][64][64] fp32 in {0,1};  W: [256][128][3][3] fp32 in {-1,0,1}
// bias: [256] integer-valued fp32; sign: [256] in {-1,+1}; out fp32 NCHW.
//
// All-integer implicit GEMM. R10: sum-of-pipes model (R3..R9 falsified
// conflicts/barriers/stores/occupancy; per-CU pipe-cycle SUM matches the
// 53 us plateau) -> reduce issued work per pipe:
//   - v_mfma_i32_32x32x32_i8: half the MFMA instructions, 11% better rate
//   - direct register->global epilogue (32x32 D-layout: lanes 0..31 are 32
//     consecutive m for one co row -> 128-B contiguous dword stores); no
//     LDS round-trip, no u8 pack/unpack, no post-loop barrier
//   - integer bias/sign epilogue (no float cvt)
//  ws: xt = i8 NHWC zero-padded [32][66][66][128], chunk-swizzled (17.8 MB)
//      wq = i8 [tap(9)][co32(8)][kstep(4)][lane(64)x16B]      (288 KB)

#define NIMG 32
#define CIN  128
#define HH   64
#define WW   64
#define COUT 256
#define PH   66                       // padded spatial
#define XT_ROWSTRIDE (PH * CIN)       // 8448 bytes per padded row
#define XT_NSTRIDE   (PH * PH * CIN)  // 557568 bytes per image
#define XT_BYTES     ((size_t)NIMG * XT_NSTRIDE)
#define WP_TAPSTRIDE (COUT * CIN)     // 32768
#define WP_BYTES     ((size_t)9 * WP_TAPSTRIDE)

typedef int   v4i  __attribute__((ext_vector_type(4)));
typedef int   v16i __attribute__((ext_vector_type(16)));

// -------------------------------------------------------------------------
// Prepass: x fp32 NCHW -> i8 NHWC (chunk-swizzled), zero-padded borders.
// Swizzle: 16-B chunk c of pixel px lands at position c ^ (px & 7).
__global__ __launch_bounds__(256) void xt_prepass(const float* __restrict__ x,
                                                  int8_t* __restrict__ xt) {
    const int py = blockIdx.x;   // 0..65
    const int n  = blockIdx.y;   // 0..31
    const int t  = threadIdx.x;
    int8_t* rowbase = xt + (size_t)(n * PH + py) * XT_ROWSTRIDE;

    if (py == 0 || py == PH - 1) {          // pure pad row: zeros
        int4 z = {0, 0, 0, 0};
        for (int j = t; j < XT_ROWSTRIDE / 16; j += 256)
            ((int4*)rowbase)[j] = z;
        return;
    }

    __shared__ __align__(16) int8_t Ls[64 * 144];  // [x][ci], +16B row pad
    const int y  = py - 1;
    const int xq = t & 15;                  // float4 index along x
    const float4* xf = (const float4*)x;
#pragma unroll
    for (int j = 0; j < 8; ++j) {
        const int ci = (t >> 4) + j * 16;   // 0..127
        float4 v = xf[((size_t)(n * CIN + ci) * HH + y) * 16 + xq];
        const int xv = xq * 4;
        Ls[(xv + 0) * 144 + ci] = (int8_t)v.x;
        Ls[(xv + 1) * 144 + ci] = (int8_t)v.y;
        Ls[(xv + 2) * 144 + ci] = (int8_t)v.z;
        Ls[(xv + 3) * 144 + ci] = (int8_t)v.w;
    }
    __syncthreads();
    const int4 z = {0, 0, 0, 0};
    for (int j = t; j < XT_ROWSTRIDE / 16; j += 256) {   // 528 int4 chunks
        const int px  = j >> 3;             // 0..65
        const int c   = j & 7;              // source chunk within pixel
        int4 val;
        if (px == 0 || px == PH - 1) val = z;
        else                         val = *(const int4*)&Ls[(px - 1) * 144 + c * 16];
        *(int4*)(rowbase + (size_t)px * CIN + ((c ^ (px & 7)) << 4)) = val;
    }
}

// -------------------------------------------------------------------------
// Weight prepack for 32x32x32: wq[tap][co32(8)][s(4)][lane*16+b]
// lane = hi*32 + (co&31), hi = (ci>>4)&1, s = ci>>5, b = ci&15.
__global__ __launch_bounds__(256) void w_prepack(const float* __restrict__ w,
                                                 int8_t* __restrict__ wq) {
    const int idx = blockIdx.x * 256 + threadIdx.x;   // 0..294911
    if (idx >= (int)WP_BYTES) return;
    const int tap = idx >> 15;          // /32768
    const int rem = idx & 32767;
    const int co  = rem >> 7;
    const int ci  = rem & 127;
    const int s = ci >> 5, hi = (ci >> 4) & 1, b = ci & 15;
    const int co32 = co >> 5, lo = co & 31;
    wq[(((tap * 8 + co32) * 4 + s) << 10) + ((hi * 32 + lo) << 4) + b] =
        (int8_t)w[(size_t)(co * CIN + ci) * 9 + tap];
}

// -------------------------------------------------------------------------
// async global->LDS, 16B/lane. LDS dest = m0 (wave-uniform) + lane*16.
__device__ __forceinline__ void glds16(const void* g, uint32_t lds_off) {
    asm volatile("s_mov_b32 m0, %0\n"
                 "global_load_lds_dwordx4 %1, off"
                 :: "s"(lds_off), "v"(g) : "memory");
}

// -------------------------------------------------------------------------
// Main GEMM: D[co][m] = sum_taps W_tap[co][ci] * X_tap[ci][m]
// block: 128co x 128m (2 output rows), 4 waves, each 64co x 64m as
// 2x2 tiles of 32x32 (acc 4 x v16i = 64 AGPR).
// X staged once (33.8 KB, swizzled); W via coalesced 1-KB fragment loads;
// no barriers after staging; direct register epilogue.
__global__ __launch_bounds__(256) void binconv_gemm(
    const int8_t* __restrict__ xt, const int8_t* __restrict__ wq,
    const float* __restrict__ bias, const float* __restrict__ sign,
    float* __restrict__ out) {

    __shared__ __align__(16) int8_t Xraw[4 * XT_ROWSTRIDE];  // 33,792 B

    const int t    = threadIdx.x;
    const int wid  = t >> 6;
    const int lane = t & 63;
    const int bx   = blockIdx.x;            // 1024 m-blocks
    const int co0  = blockIdx.y * 128;      // 0 / 128
    const int n    = bx >> 5;
    const int y0   = (bx & 31) << 1;        // 2 output rows per block

    // ---- stage 4 padded rows (33 KiB) verbatim, once ----
    const int8_t* xbase = xt + (size_t)n * XT_NSTRIDE + (size_t)y0 * XT_ROWSTRIDE;
    {
        const int8_t* gsrc = xbase + lane * 16;
        const uint32_t lds0 = (uint32_t)(uintptr_t)Xraw;
        for (int j = wid; j < 33; j += 4)
            glds16(gsrc + j * 1024,
                   __builtin_amdgcn_readfirstlane(lds0 + j * 1024));
        asm volatile("s_waitcnt vmcnt(0)" ::: "memory");
        __syncthreads();
    }

    const int m_lo = lane & 31;             // m within 32-tile; D col
    const int hi   = lane >> 5;             // k-half for A/B operands
    const int co_off = (wid >> 1) * 64;
    const int yw     = wid & 1;             // wave's output row in {y0,y0+1}
    const int ct0  = (co0 + co_off) >> 5;   // first co32 tile (global idx)

    const int8_t* Xw  = Xraw + yw * XT_ROWSTRIDE;
    const int8_t* wqb = wq + lane * 16;

    v16i acc[2][2] = {};                    // [ct][mt]

#pragma unroll
    for (int tap = 0; tap < 9; ++tap) {
        const int ky = tap / 3, kx = tap % 3;
        const int8_t* xl = Xw + ky * XT_ROWSTRIDE;
        const int px0 = m_lo + kx;          // pixel for mt=0
        const int pk  = px0 & 7;            // swizzle key (same both mt)

        v4i af[2][4];                       // [ct][s]
#pragma unroll
        for (int c = 0; c < 2; ++c)
#pragma unroll
            for (int s = 0; s < 4; ++s)
                af[c][s] = *(const v4i*)(wqb
                    + ((((tap * 8 + ct0 + c) * 4) + s) << 10));

        const int8_t* xb = xl + px0 * CIN;  // lane's pixel base (mt=0)
        v4i bf[2][4];                       // [mt][s]
#pragma unroll
        for (int s = 0; s < 4; ++s) {
            const int sw = ((2 * s + hi) ^ pk) << 4;
#pragma unroll
            for (int m = 0; m < 2; ++m)
                bf[m][s] = *(const v4i*)(xb + m * 32 * CIN + sw);
        }
#pragma unroll
        for (int s = 0; s < 4; ++s)
#pragma unroll
            for (int c = 0; c < 2; ++c)
#pragma unroll
                for (int m = 0; m < 2; ++m)
                    acc[c][m] = __builtin_amdgcn_mfma_i32_32x32x32_i8(
                        af[c][s], bf[m][s], acc[c][m], 0, 0, 0);
    }

    // ---- epilogue: direct from registers.
    // D 32x32 layout: col(m) = lane&31, row(co) = (r&3)+8*(r>>2)+4*hi.
    const float* bco = bias + co0 + co_off;
    const float* sco = sign + co0 + co_off;
    float* outb = out + ((size_t)n * COUT + co0 + co_off) * (HH * WW)
                + (y0 + yw) * WW;
#pragma unroll
    for (int c = 0; c < 2; ++c) {
#pragma unroll
        for (int r = 0; r < 16; ++r) {
            const int co_l = c * 32 + (r & 3) + 8 * (r >> 2) + 4 * hi;
            const int bi = (int)bco[co_l];
            const int si = (int)sco[co_l];         // +-1
            float* orow = outb + (size_t)co_l * (HH * WW);
#pragma unroll
            for (int m = 0; m < 2; ++m) {
                const int tv = (acc[c][m][r] + bi) * si;
                orow[m * 32 + m_lo] = (tv >= 0) ? 1.0f : 0.0f;
            }
        }
    }
}

// -------------------------------------------------------------------------
// Fallback (only if ws too small): naive direct conv, one thread per output.
__global__ __launch_bounds__(256) void naive_conv(
    const float* __restrict__ x, const float* __restrict__ w,
    const float* __restrict__ bias, const float* __restrict__ sign,
    float* __restrict__ out) {
    const int idx = blockIdx.x * 256 + threadIdx.x;
    const int xc = idx & 63, y = (idx >> 6) & 63, co = (idx >> 12) & 255,
              n = idx >> 20;
    float s = 0.f;
    for (int ci = 0; ci < CIN; ++ci)
        for (int ky = 0; ky < 3; ++ky) {
            const int iy = y + ky - 1;
            if (iy < 0 || iy >= HH) continue;
            for (int kx = 0; kx < 3; ++kx) {
                const int ix = xc + kx - 1;
                if (ix < 0 || ix >= WW) continue;
                s += x[((size_t)(n * CIN + ci) * HH + iy) * WW + ix] *
                     w[((size_t)(co * CIN + ci) * 3 + ky) * 3 + kx];
            }
        }
    const float yv = s + bias[co];
    out[idx] = ((sign[co] > 0.f) ? (yv >= 0.f) : (yv <= 0.f)) ? 1.0f : 0.0f;
}

// -------------------------------------------------------------------------
extern "C" void kernel_launch(void* const* d_in, const int* in_sizes, int n_in,
                              void* d_out, int out_size, void* d_ws, size_t ws_size,
                              hipStream_t stream) {
    const float* x    = (const float*)d_in[0];
    const float* w    = (const float*)d_in[1];
    const float* bias = (const float*)d_in[2];
    const float* sign = (const float*)d_in[3];
    float* out = (float*)d_out;

    const size_t need = XT_BYTES + WP_BYTES;   // ~18.1 MiB
    if (ws_size < need) {
        naive_conv<<<dim3((NIMG * COUT * HH * WW) / 256), 256, 0, stream>>>(
            x, w, bias, sign, out);
        return;
    }
    int8_t* xt = (int8_t*)d_ws;
    int8_t* wq = (int8_t*)d_ws + XT_BYTES;

    xt_prepass<<<dim3(PH, NIMG), 256, 0, stream>>>(x, xt);
    w_prepack<<<dim3((int)(WP_BYTES + 255) / 256), 256, 0, stream>>>(w, wq);
    binconv_gemm<<<dim3(NIMG * (HH / 2), COUT / 128), 256, 0, stream>>>(
        xt, wq, bias, sign, out);
}

// Round 11
// 209.250 us; speedup vs baseline: 1.0909x; 1.0909x over previous
//
#include <hip/hip_runtime.h>
#include <cstdint>

// BinConv2dEval: y = conv3x3(x,W) + bias; out = (sign*y >= 0) ? 1 : 0
// x: [32][128][64][64] fp32 in {0,1};  W: [256][128][3][3] fp32 in {-1,0,1}
// bias: [256] integer-valued fp32; sign: [256] in {-1,+1}; out fp32 NCHW.
//
// R11: MX-FP4 implicit GEMM. x/w are exactly fp4-representable; the
// mfma_scale_f32_32x32x64_f8f6f4 (fp4, scale=2^0) runs at ~2x the i8 rate
// AND halves operand bytes on every pipe (LDS, W loads, staging). fp32
// accumulation is exact (|sums| <= 1352 << 2^24). Sum-of-pipes model
// (R3..R10: conflicts/barriers/stores/occupancy each falsified as single
// binders) says cutting all pipes together is the remaining lever.
// Epilogue = R8's proven LDS-transpose -> 256-B NT bursts.
//  ws: xt4 = fp4 NHWC zero-padded [32][66][66][128/2 B], chunk-swizzled
//       (8.9 MB; 16-B chunk c of pixel px stored at c^(px&3))
//      wq4 = fp4 fragment-major [tap(9)][co32(8)][s(2)][lane(64)x16B] (144 KB)

#define NIMG 32
#define CIN  128
#define HH   64
#define WW   64
#define COUT 256
#define PH   66
#define X4_ROW 4224                    // 66 px * 64 B
#define X4_IMG (PH * X4_ROW)           // 278784
#define X4_BYTES ((size_t)NIMG * X4_IMG)
#define WQ4_BYTES ((size_t)9 * 8 * 2 * 64 * 16)   // 147456

typedef int   v4i  __attribute__((ext_vector_type(4)));
typedef int   v8i  __attribute__((ext_vector_type(8)));
typedef float v16f __attribute__((ext_vector_type(16)));
typedef float v4f  __attribute__((ext_vector_type(4)));

// -------------------------------------------------------------------------
// Prepass: x fp32 NCHW -> fp4 NHWC (nibble-packed, chunk-swizzled), padded.
// fp4 e2m1: 1.0 -> 0x2, 0 -> 0x0.
__device__ __forceinline__ uint32_t pack4(uint32_t u) {
    // 4 bytes in {0,1} -> 4 fp4 nibbles {0x0,0x2} in low 16 bits
    const uint32_t tt = (u & 0x01010101u) << 1;
    return (tt & 0xFu) | ((tt >> 4) & 0xF0u) | ((tt >> 8) & 0xF00u)
         | ((tt >> 12) & 0xF000u);
}

__global__ __launch_bounds__(256) void xt_prepass(const float* __restrict__ x,
                                                  int8_t* __restrict__ xt4) {
    const int py = blockIdx.x;   // 0..65
    const int n  = blockIdx.y;   // 0..31
    const int t  = threadIdx.x;
    int8_t* rowbase = xt4 + (size_t)(n * PH + py) * X4_ROW;

    if (py == 0 || py == PH - 1) {          // pure pad row: zeros
        int4 z = {0, 0, 0, 0};
        for (int j = t; j < X4_ROW / 16; j += 256)
            ((int4*)rowbase)[j] = z;
        return;
    }

    __shared__ __align__(16) int8_t Ls[64 * 144];  // [x][ci] bytes {0,1}
    const int y  = py - 1;
    const int xq = t & 15;
    const float4* xf = (const float4*)x;
#pragma unroll
    for (int j = 0; j < 8; ++j) {
        const int ci = (t >> 4) + j * 16;
        float4 v = xf[((size_t)(n * CIN + ci) * HH + y) * 16 + xq];
        const int xv = xq * 4;
        Ls[(xv + 0) * 144 + ci] = (int8_t)v.x;
        Ls[(xv + 1) * 144 + ci] = (int8_t)v.y;
        Ls[(xv + 2) * 144 + ci] = (int8_t)v.z;
        Ls[(xv + 3) * 144 + ci] = (int8_t)v.w;
    }
    __syncthreads();
    for (int j = t; j < 264; j += 256) {    // 264 16-B output chunks
        const int px = j >> 2;              // 0..65
        const int c  = j & 3;               // chunk = 32 ci
        int4 o = {0, 0, 0, 0};
        if (px != 0 && px != PH - 1) {
            const int4* lp = (const int4*)&Ls[(px - 1) * 144 + c * 32];
            const int4 a = lp[0], b = lp[1];   // 32 bytes = 32 ci
            o.x = (int)(pack4((uint32_t)a.x) | (pack4((uint32_t)a.y) << 16));
            o.y = (int)(pack4((uint32_t)a.z) | (pack4((uint32_t)a.w) << 16));
            o.z = (int)(pack4((uint32_t)b.x) | (pack4((uint32_t)b.y) << 16));
            o.w = (int)(pack4((uint32_t)b.z) | (pack4((uint32_t)b.w) << 16));
        }
        *(int4*)(rowbase + (size_t)px * 64 + ((c ^ (px & 3)) << 4)) = o;
    }
}

// -------------------------------------------------------------------------
// Weight prepack: OIHW fp32 -> fp4 fragment-major wq4.
// Lane layout (32x32x64 A): m=co= lane&31, k = (lane>>5)*32 + e; tap K=128
// split as s(2) x 64. One thread per output BYTE (2 ci nibbles).
__global__ __launch_bounds__(256) void w_prepack(const float* __restrict__ w,
                                                 int8_t* __restrict__ wq4) {
    const int idx = blockIdx.x * 256 + threadIdx.x;   // 0..147455
    if (idx >= (int)WQ4_BYTES) return;
    const int b    = idx & 15;
    const int lane = (idx >> 4) & 63;
    const int s    = (idx >> 10) & 1;
    const int co32 = (idx >> 11) & 7;
    const int tap  = idx >> 14;             // 0..8
    const int co   = co32 * 32 + (lane & 31);
    const int ci0  = s * 64 + (lane >> 5) * 32 + b * 2;
    const int i0 = (int)w[(size_t)(co * CIN + ci0) * 9 + tap];
    const int i1 = (int)w[(size_t)(co * CIN + ci0 + 1) * 9 + tap];
    const uint32_t n0 = (i0 == 0) ? 0u : ((i0 > 0) ? 0x2u : 0xAu);
    const uint32_t n1 = (i1 == 0) ? 0u : ((i1 > 0) ? 0x2u : 0xAu);
    wq4[idx] = (int8_t)(n0 | (n1 << 4));
}

// -------------------------------------------------------------------------
// async global->LDS, 16B/lane.
__device__ __forceinline__ void glds16(const void* g, uint32_t lds_off) {
    asm volatile("s_mov_b32 m0, %0\n"
                 "global_load_lds_dwordx4 %1, off"
                 :: "s"(lds_off), "v"(g) : "memory");
}

__device__ __forceinline__ v8i widen(v4i x) {
    v8i r = {x[0], x[1], x[2], x[3], 0, 0, 0, 0};   // fp4 uses low 4 regs
    return r;
}

// -------------------------------------------------------------------------
// Main GEMM: block 128co x 128m (2 output rows), 4 waves = 64co x 64m each
// as 2x2 of 32x32 tiles. X strip (4 padded rows, 16.9 KB fp4) staged once;
// W via 1-KB coalesced fragment loads; barrier-free K-loop; NT epilogue.
__global__ __launch_bounds__(256) void binconv_gemm(
    const int8_t* __restrict__ xt4, const int8_t* __restrict__ wq4,
    const float* __restrict__ bias, const float* __restrict__ sign,
    float* __restrict__ out) {

    __shared__ __align__(16) int8_t Xraw[17 * 1024];  // strip 16896 B + pad

    const int t    = threadIdx.x;
    const int wid  = t >> 6;
    const int lane = t & 63;
    const int bx   = blockIdx.x;            // 1024
    const int co0  = blockIdx.y * 128;
    const int n    = bx >> 5;
    const int y0   = (bx & 31) << 1;

    // ---- stage 4 padded fp4 rows once (17 x 1KB; tail over-read stays in ws)
    const int8_t* xbase = xt4 + (size_t)n * X4_IMG + (size_t)y0 * X4_ROW;
    {
        const int8_t* gsrc = xbase + lane * 16;
        const uint32_t lds0 = (uint32_t)(uintptr_t)Xraw;
        for (int j = wid; j < 17; j += 4)
            glds16(gsrc + j * 1024,
                   __builtin_amdgcn_readfirstlane(lds0 + j * 1024));
        asm volatile("s_waitcnt vmcnt(0)" ::: "memory");
        __syncthreads();
    }

    const int m_lo = lane & 31;             // D col (m); A co row
    const int hi   = lane >> 5;             // k-half
    const int co_off = (wid >> 1) * 64;
    const int yw     = wid & 1;
    const int ct0    = (co0 + co_off) >> 5; // first co32 tile

    const int8_t* Xw   = Xraw + yw * X4_ROW;
    const int8_t* wqb  = wq4 + lane * 16;

    v16f acc[2][2] = {};                    // [ct][mt], fp32 exact

#pragma unroll
    for (int tap = 0; tap < 9; ++tap) {
        const int ky = tap / 3, kx = tap % 3;
        const int8_t* xl = Xw + ky * X4_ROW;
        const int px0 = m_lo + kx;
        const int pk  = px0 & 3;            // same for both mt (32%4==0)

        v4i af[2][2];                       // [ct][s] 16B fragments
#pragma unroll
        for (int c = 0; c < 2; ++c)
#pragma unroll
            for (int s = 0; s < 2; ++s)
                af[c][s] = *(const v4i*)(wqb
                    + ((((tap * 8 + ct0 + c) * 2) + s) << 10));

        v4i bf[2][2];                       // [mt][s]
#pragma unroll
        for (int s = 0; s < 2; ++s) {
            const int sw = (((s << 1) + hi) ^ pk) << 4;
#pragma unroll
            for (int m = 0; m < 2; ++m)
                bf[m][s] = *(const v4i*)(xl + (px0 + m * 32) * 64 + sw);
        }
#pragma unroll
        for (int s = 0; s < 2; ++s)
#pragma unroll
            for (int c = 0; c < 2; ++c)
#pragma unroll
                for (int m = 0; m < 2; ++m)
                    acc[c][m] = __builtin_amdgcn_mfma_scale_f32_32x32x64_f8f6f4(
                        widen(af[c][s]), widen(bf[m][s]), acc[c][m],
                        4, 4,             // cbsz=fp4, blgp=fp4
                        0, 0x7F7F7F7F,    // scale_a = 2^0
                        0, 0x7F7F7F7F);   // scale_b = 2^0
    }

    // ---- epilogue: threshold -> u8 LDS transpose -> 256-B NT bursts
    __syncthreads();                        // strip reads done
    int8_t* Lep = Xraw + wid * 4096;        // wave-private [co64][m64] u8

    const float* bco = bias + co0 + co_off;
    const float* sco = sign + co0 + co_off;
#pragma unroll
    for (int c = 0; c < 2; ++c) {
#pragma unroll
        for (int r = 0; r < 16; ++r) {
            const int co_l = c * 32 + (r & 3) + 8 * (r >> 2) + 4 * hi;
            const float bv = bco[co_l];
            const float sv = sco[co_l];
#pragma unroll
            for (int m = 0; m < 2; ++m) {
                const float yv = acc[c][m][r] + bv;     // exact integer
                const bool on = (sv > 0.0f) ? (yv >= 0.0f) : (yv <= 0.0f);
                Lep[co_l * 64 + m * 32 + m_lo] = (int8_t)on;
            }
        }
    }
    const int r16 = lane & 15, q4 = lane >> 4;
    float* outb = out + ((size_t)n * COUT + co0 + co_off) * (HH * WW)
                + (y0 + yw) * WW;
#pragma unroll
    for (int g = 0; g < 16; ++g) {
        const int p = g * 4 + q4;           // co plane within the 64
        const uint32_t u = *(const uint32_t*)&Lep[p * 64 + r16 * 4];
        v4f v;
        v.x = (float)( u        & 0xff);
        v.y = (float)((u >>  8) & 0xff);
        v.z = (float)((u >> 16) & 0xff);
        v.w = (float)((u >> 24) & 0xff);
        __builtin_nontemporal_store(v,
            (v4f*)(outb + (size_t)p * (HH * WW) + r16 * 4));
    }
}

// -------------------------------------------------------------------------
// Fallback (only if ws too small): naive direct conv.
__global__ __launch_bounds__(256) void naive_conv(
    const float* __restrict__ x, const float* __restrict__ w,
    const float* __restrict__ bias, const float* __restrict__ sign,
    float* __restrict__ out) {
    const int idx = blockIdx.x * 256 + threadIdx.x;
    const int xc = idx & 63, y = (idx >> 6) & 63, co = (idx >> 12) & 255,
              n = idx >> 20;
    float s = 0.f;
    for (int ci = 0; ci < CIN; ++ci)
        for (int ky = 0; ky < 3; ++ky) {
            const int iy = y + ky - 1;
            if (iy < 0 || iy >= HH) continue;
            for (int kx = 0; kx < 3; ++kx) {
                const int ix = xc + kx - 1;
                if (ix < 0 || ix >= WW) continue;
                s += x[((size_t)(n * CIN + ci) * HH + iy) * WW + ix] *
                     w[((size_t)(co * CIN + ci) * 3 + ky) * 3 + kx];
            }
        }
    const float yv = s + bias[co];
    out[idx] = ((sign[co] > 0.f) ? (yv >= 0.f) : (yv <= 0.f)) ? 1.0f : 0.0f;
}

// -------------------------------------------------------------------------
extern "C" void kernel_launch(void* const* d_in, const int* in_sizes, int n_in,
                              void* d_out, int out_size, void* d_ws, size_t ws_size,
                              hipStream_t stream) {
    const float* x    = (const float*)d_in[0];
    const float* w    = (const float*)d_in[1];
    const float* bias = (const float*)d_in[2];
    const float* sign = (const float*)d_in[3];
    float* out = (float*)d_out;

    const size_t need = X4_BYTES + WQ4_BYTES + 1024;   // ~9.1 MiB (+tail pad)
    if (ws_size < need) {
        naive_conv<<<dim3((NIMG * COUT * HH * WW) / 256), 256, 0, stream>>>(
            x, w, bias, sign, out);
        return;
    }
    int8_t* xt4 = (int8_t*)d_ws;
    int8_t* wq4 = (int8_t*)d_ws + X4_BYTES;

    xt_prepass<<<dim3(PH, NIMG), 256, 0, stream>>>(x, xt4);
    w_prepack<<<dim3((int)((WQ4_BYTES + 255) / 256)), 256, 0, stream>>>(w, wq4);
    binconv_gemm<<<dim3(NIMG * (HH / 2), COUT / 128), 256, 0, stream>>>(
        xt4, wq4, bias, sign, out);
}

// Round 12
// 207.533 us; speedup vs baseline: 1.0999x; 1.0083x over previous
//
#include <hip/hip_runtime.h>
#include <cstdint>

// BinConv2dEval: y = conv3x3(x,W) + bias; out = (sign*y >= 0) ? 1 : 0
// x: [32][128][64][64] fp32 in {0,1};  W: [256][128][3][3] fp32 in {-1,0,1}
// bias: [256] integer-valued fp32; sign: [256] in {-1,+1}; out fp32 NCHW.
//
// R11 (kept): MX-FP4 GEMM, mfma_scale_f32_32x32x64_f8f6f4 (exact: sums
// << 2^24), chunk-swizzled pixel blocks, NT-burst epilogue. VERIFIED.
// R12: FUSION. Sum-of-pipes says the GEMM loop is near its additive floor;
// the big remaining terms were the separate prepass kernel (~15 us, 67 MB
// x read + xt4 round-trip) and launch boundaries. Now each block builds
// its own fp4 X-strip in LDS straight from x:
//   Phase A: 512 thr x one (row,ci) 256-B run, {0,1}f32 -> fp4 nibble via
//            (bits>>28)&2, nibble-bytes to 68-pad staging (bank-free).
//   Phase B: 264 thr transpose columns -> swizzled 64-B pixel blocks
//            (identical layout to R11's verified K-loop input).
//   Phase C: 8 waves = 256co x 128m (64co x 64m each, acc 64 AGPR).
// One x read per block (no co-half duplication), no xt4, no glds16,
// no pre-epilogue barrier (Lep reuses the dead staging region).
//  ws: wq4 = fp4 fragment-major [tap(9)][co32(8)][s(2)][lane(64)x16B] (144 KB)

#define NIMG 32
#define CIN  128
#define HH   64
#define WW   64
#define COUT 256
#define PH   66
#define X4ROW   4224                  // 66 px * 64 B
#define STG_ROW 8704                  // 128 ci * 68 B (pad vs bank conflicts)
#define STG_BYTES (4 * STG_ROW)       // 34816
#define LDS_TOTAL (STG_BYTES + 4 * X4ROW)   // 51712
#define WQ4_BYTES ((size_t)9 * 8 * 2 * 64 * 16)   // 147456

typedef int   v4i  __attribute__((ext_vector_type(4)));
typedef int   v8i  __attribute__((ext_vector_type(8)));
typedef float v16f __attribute__((ext_vector_type(16)));
typedef float v4f  __attribute__((ext_vector_type(4)));

// -------------------------------------------------------------------------
// Weight prepack: OIHW fp32 -> fp4 fragment-major wq4 (verified R11).
// Lane layout (32x32x64 A): co = lane&31, k = (lane>>5)*32 + e; K=128 as
// s(2) x 64. One thread per output byte (2 ci nibbles, low = even ci).
__global__ __launch_bounds__(256) void w_prepack(const float* __restrict__ w,
                                                 int8_t* __restrict__ wq4) {
    const int idx = blockIdx.x * 256 + threadIdx.x;   // 0..147455
    if (idx >= (int)WQ4_BYTES) return;
    const int b    = idx & 15;
    const int lane = (idx >> 4) & 63;
    const int s    = (idx >> 10) & 1;
    const int co32 = (idx >> 11) & 7;
    const int tap  = idx >> 14;             // 0..8
    const int co   = co32 * 32 + (lane & 31);
    const int ci0  = s * 64 + (lane >> 5) * 32 + b * 2;
    const int i0 = (int)w[(size_t)(co * CIN + ci0) * 9 + tap];
    const int i1 = (int)w[(size_t)(co * CIN + ci0 + 1) * 9 + tap];
    const uint32_t n0 = (i0 == 0) ? 0u : ((i0 > 0) ? 0x2u : 0xAu);
    const uint32_t n1 = (i1 == 0) ? 0u : ((i1 > 0) ? 0x2u : 0xAu);
    wq4[idx] = (int8_t)(n0 | (n1 << 4));
}

__device__ __forceinline__ v8i widen(v4i x) {
    v8i r = {x[0], x[1], x[2], x[3], 0, 0, 0, 0};   // fp4 uses low 4 regs
    return r;
}

// -------------------------------------------------------------------------
// Fused kernel: build fp4 X-strip in LDS from x, then MX-FP4 GEMM.
// grid 1024 = n(32) x ystrip(32); block 512 = 8 waves (256co x 128m).
__global__ __launch_bounds__(512) void binconv_fused(
    const float* __restrict__ x, const int8_t* __restrict__ wq4,
    const float* __restrict__ bias, const float* __restrict__ sign,
    float* __restrict__ out) {

    __shared__ __align__(16) int8_t Smem[LDS_TOTAL];
    int8_t* Stg = Smem;                 // [4 row][128 ci][68] nibble bytes
    int8_t* X4  = Smem + STG_BYTES;     // [4 row][66 px][64 B] fp4 swizzled

    const int t  = threadIdx.x;
    const int bx = blockIdx.x;
    const int n  = bx >> 5;
    const int y0 = (bx & 31) << 1;      // 2 output rows per block

    // ---- Phase A: raw x -> nibble bytes in staging ----
    {
        const int sy = t >> 7;          // strip row 0..3
        const int ci = t & 127;
        const int y  = y0 + sy - 1;     // raw image row
        uint32_t* sp = (uint32_t*)(Stg + sy * STG_ROW + ci * 68);
        if (y >= 0 && y < HH) {
            const float4* xr =
                (const float4*)(x + (((size_t)n * CIN + ci) * HH + y) * WW);
#pragma unroll
            for (int q = 0; q < 16; ++q) {
                float4 v = xr[q];
                const uint32_t b0 = (__float_as_uint(v.x) >> 28) & 2u;
                const uint32_t b1 = (__float_as_uint(v.y) >> 28) & 2u;
                const uint32_t b2 = (__float_as_uint(v.z) >> 28) & 2u;
                const uint32_t b3 = (__float_as_uint(v.w) >> 28) & 2u;
                sp[q] = b0 | (b1 << 8) | (b2 << 16) | (b3 << 24);
            }
        } else {
#pragma unroll
            for (int q = 0; q < 16; ++q) sp[q] = 0u;
        }
    }
    __syncthreads();

    // ---- Phase B: transpose -> swizzled fp4 pixel blocks ----
    if (t < 264) {
        const int sy  = t / 66;
        const int pxp = t - sy * 66;    // padded pixel 0..65
        int8_t* dst = X4 + sy * X4ROW + pxp * 64;
        if (pxp == 0 || pxp == 65) {
            const int4 z = {0, 0, 0, 0};
#pragma unroll
            for (int c = 0; c < 4; ++c) *(int4*)(dst + c * 16) = z;
        } else {
            const int8_t* src = Stg + sy * STG_ROW + (pxp - 1);
            uint32_t wrd[16];
#pragma unroll
            for (int k = 0; k < 16; ++k) {
                uint32_t a = 0;
#pragma unroll
                for (int b = 0; b < 4; ++b) {
                    const int j = k * 4 + b;          // byte = ci-pair
                    const uint32_t lo = (uint8_t)src[(2 * j)     * 68];
                    const uint32_t hi = (uint8_t)src[(2 * j + 1) * 68];
                    a |= (lo | (hi << 4)) << (8 * b);
                }
                wrd[k] = a;
            }
            const int sk = pxp & 3;     // chunk swizzle key
#pragma unroll
            for (int c = 0; c < 4; ++c) {
                int4 vv = {(int)wrd[c*4], (int)wrd[c*4+1],
                           (int)wrd[c*4+2], (int)wrd[c*4+3]};
                *(int4*)(dst + ((c ^ sk) << 4)) = vv;
            }
        }
    }
    __syncthreads();

    // ---- Phase C: GEMM ----
    const int wid  = t >> 6;            // 0..7
    const int lane = t & 63;
    const int m_lo = lane & 31;         // D col (m); A co row
    const int hi   = lane >> 5;         // k-half
    const int co_off = (wid >> 1) * 64; // 0,64,128,192
    const int yw     = wid & 1;         // output row y0 / y0+1
    const int ct0    = co_off >> 5;     // first co32 tile

    const int8_t* Xw  = X4 + yw * X4ROW;
    const int8_t* wqb = wq4 + lane * 16;

    v16f acc[2][2] = {};                // [ct][mt], fp32 exact

#pragma unroll
    for (int tap = 0; tap < 9; ++tap) {
        const int ky = tap / 3, kx = tap % 3;
        const int8_t* xl = Xw + ky * X4ROW;
        const int px0 = m_lo + kx;
        const int pk  = px0 & 3;

        v4i af[2][2];                   // [ct][s]
#pragma unroll
        for (int c = 0; c < 2; ++c)
#pragma unroll
            for (int s = 0; s < 2; ++s)
                af[c][s] = *(const v4i*)(wqb
                    + ((((tap * 8 + ct0 + c) * 2) + s) << 10));

        v4i bf[2][2];                   // [mt][s]
#pragma unroll
        for (int s = 0; s < 2; ++s) {
            const int sw = (((s << 1) + hi) ^ pk) << 4;
#pragma unroll
            for (int m = 0; m < 2; ++m)
                bf[m][s] = *(const v4i*)(xl + (px0 + m * 32) * 64 + sw);
        }
#pragma unroll
        for (int s = 0; s < 2; ++s)
#pragma unroll
            for (int c = 0; c < 2; ++c)
#pragma unroll
                for (int m = 0; m < 2; ++m)
                    acc[c][m] = __builtin_amdgcn_mfma_scale_f32_32x32x64_f8f6f4(
                        widen(af[c][s]), widen(bf[m][s]), acc[c][m],
                        4, 4,             // cbsz=fp4, blgp=fp4
                        0, 0x7F7F7F7F,    // scale_a = 2^0
                        0, 0x7F7F7F7F);   // scale_b = 2^0
    }

    // ---- epilogue: threshold -> u8 LDS transpose -> 256-B NT bursts.
    // Lep lives in the dead staging region (8 waves x 4 KB = 32 KB), so no
    // barrier needed (X4 region untouched; Lep is wave-private).
    int8_t* Lep = Smem + wid * 4096;

    const float* bco = bias + co_off;
    const float* sco = sign + co_off;
#pragma unroll
    for (int c = 0; c < 2; ++c) {
#pragma unroll
        for (int r = 0; r < 16; ++r) {
            const int co_l = c * 32 + (r & 3) + 8 * (r >> 2) + 4 * hi;
            const float bv = bco[co_l];
            const float sv = sco[co_l];
#pragma unroll
            for (int m = 0; m < 2; ++m) {
                const float yv = acc[c][m][r] + bv;     // exact integer
                const bool on = (sv > 0.0f) ? (yv >= 0.0f) : (yv <= 0.0f);
                Lep[co_l * 64 + m * 32 + m_lo] = (int8_t)on;
            }
        }
    }
    const int r16 = lane & 15, q4 = lane >> 4;
    float* outb = out + ((size_t)n * COUT + co_off) * (HH * WW)
                + (y0 + yw) * WW;
#pragma unroll
    for (int g = 0; g < 16; ++g) {
        const int p = g * 4 + q4;       // co plane within the 64
        const uint32_t u = *(const uint32_t*)&Lep[p * 64 + r16 * 4];
        v4f v;
        v.x = (float)( u        & 0xff);
        v.y = (float)((u >>  8) & 0xff);
        v.z = (float)((u >> 16) & 0xff);
        v.w = (float)((u >> 24) & 0xff);
        __builtin_nontemporal_store(v,
            (v4f*)(outb + (size_t)p * (HH * WW) + r16 * 4));
    }
}

// -------------------------------------------------------------------------
// Fallback (only if ws too small): naive direct conv.
__global__ __launch_bounds__(256) void naive_conv(
    const float* __restrict__ x, const float* __restrict__ w,
    const float* __restrict__ bias, const float* __restrict__ sign,
    float* __restrict__ out) {
    const int idx = blockIdx.x * 256 + threadIdx.x;
    const int xc = idx & 63, y = (idx >> 6) & 63, co = (idx >> 12) & 255,
              n = idx >> 20;
    float s = 0.f;
    for (int ci = 0; ci < CIN; ++ci)
        for (int ky = 0; ky < 3; ++ky) {
            const int iy = y + ky - 1;
            if (iy < 0 || iy >= HH) continue;
            for (int kx = 0; kx < 3; ++kx) {
                const int ix = xc + kx - 1;
                if (ix < 0 || ix >= WW) continue;
                s += x[((size_t)(n * CIN + ci) * HH + iy) * WW + ix] *
                     w[((size_t)(co * CIN + ci) * 3 + ky) * 3 + kx];
            }
        }
    const float yv = s + bias[co];
    out[idx] = ((sign[co] > 0.f) ? (yv >= 0.f) : (yv <= 0.f)) ? 1.0f : 0.0f;
}

// -------------------------------------------------------------------------
extern "C" void kernel_launch(void* const* d_in, const int* in_sizes, int n_in,
                              void* d_out, int out_size, void* d_ws, size_t ws_size,
                              hipStream_t stream) {
    const float* x    = (const float*)d_in[0];
    const float* w    = (const float*)d_in[1];
    const float* bias = (const float*)d_in[2];
    const float* sign = (const float*)d_in[3];
    float* out = (float*)d_out;

    if (ws_size < WQ4_BYTES) {
        naive_conv<<<dim3((NIMG * COUT * HH * WW) / 256), 256, 0, stream>>>(
            x, w, bias, sign, out);
        return;
    }
    int8_t* wq4 = (int8_t*)d_ws;

    w_prepack<<<dim3((int)((WQ4_BYTES + 255) / 256)), 256, 0, stream>>>(w, wq4);
    binconv_fused<<<dim3(NIMG * (HH / 2)), 512, 0, stream>>>(
        x, wq4, bias, sign, out);
}

// Round 13
// 206.160 us; speedup vs baseline: 1.1073x; 1.0067x over previous
//
#include <hip/hip_runtime.h>
#include <cstdint>

// BinConv2dEval: y = conv3x3(x,W) + bias; out = (sign*y >= 0) ? 1 : 0
// x: [32][128][64][64] fp32 in {0,1};  W: [256][128][3][3] fp32 in {-1,0,1}
// bias: [256] integer-valued fp32; sign: [256] in {-1,+1}; out fp32 NCHW.
//
// R11/R12 (kept, verified): MX-FP4 fused GEMM — per-block LDS build of the
// swizzled fp4 X-strip, mfma_scale_f32_32x32x64_f8f6f4 (exact), 8 waves =
// 256co x 128m. R13: cut LDS-pipe instruction count ~55%:
//   A: 256 thr x ci-PAIR loads -> staging holds final nibble-pair bytes
//      [sy][cipair 64][px 64+4 pad]  (A-writes halve; B repack removed)
//   B: 64 b8 reads + 4 swizzled b128 writes (same verified pattern)
//   epilogue: DIRECT NT dword stores from acc (no Lep LDS round-trip;
//      -640 ds-inst/block for +384 vmem)
//  ws: wq4 = fp4 fragment-major [tap(9)][co32(8)][s(2)][lane(64)x16B] (144 KB)

#define NIMG 32
#define CIN  128
#define HH   64
#define WW   64
#define COUT 256
#define X4ROW   4224                  // 66 px * 64 B
#define STG_SY  4352                  // 64 cipair * 68 B
#define STG_BYTES (4 * STG_SY)        // 17408
#define LDS_TOTAL (STG_BYTES + 4 * X4ROW)   // 34304
#define WQ4_BYTES ((size_t)9 * 8 * 2 * 64 * 16)   // 147456

typedef int   v4i  __attribute__((ext_vector_type(4)));
typedef int   v8i  __attribute__((ext_vector_type(8)));
typedef float v16f __attribute__((ext_vector_type(16)));

// -------------------------------------------------------------------------
// Weight prepack: OIHW fp32 -> fp4 fragment-major wq4 (verified R11/R12).
// byte b of a fragment = ci pair (2b even -> low nibble, 2b+1 -> high).
__global__ __launch_bounds__(256) void w_prepack(const float* __restrict__ w,
                                                 int8_t* __restrict__ wq4) {
    const int idx = blockIdx.x * 256 + threadIdx.x;   // 0..147455
    if (idx >= (int)WQ4_BYTES) return;
    const int b    = idx & 15;
    const int lane = (idx >> 4) & 63;
    const int s    = (idx >> 10) & 1;
    const int co32 = (idx >> 11) & 7;
    const int tap  = idx >> 14;             // 0..8
    const int co   = co32 * 32 + (lane & 31);
    const int ci0  = s * 64 + (lane >> 5) * 32 + b * 2;
    const int i0 = (int)w[(size_t)(co * CIN + ci0) * 9 + tap];
    const int i1 = (int)w[(size_t)(co * CIN + ci0 + 1) * 9 + tap];
    const uint32_t n0 = (i0 == 0) ? 0u : ((i0 > 0) ? 0x2u : 0xAu);
    const uint32_t n1 = (i1 == 0) ? 0u : ((i1 > 0) ? 0x2u : 0xAu);
    wq4[idx] = (int8_t)(n0 | (n1 << 4));
}

__device__ __forceinline__ v8i widen(v4i x) {
    v8i r = {x[0], x[1], x[2], x[3], 0, 0, 0, 0};   // fp4 uses low 4 regs
    return r;
}

// -------------------------------------------------------------------------
// Fused kernel. grid 1024 = n(32) x ystrip(32); block 512 = 8 waves.
__global__ __launch_bounds__(512) void binconv_fused(
    const float* __restrict__ x, const int8_t* __restrict__ wq4,
    const float* __restrict__ bias, const float* __restrict__ sign,
    float* __restrict__ out) {

    __shared__ __align__(16) int8_t Smem[LDS_TOTAL];
    int8_t* Stg = Smem;                 // [4 sy][64 cipair][68] nibble-pair bytes
    int8_t* X4  = Smem + STG_BYTES;     // [4 sy][66 px][64 B] fp4 swizzled

    const int t  = threadIdx.x;
    const int bx = blockIdx.x;
    const int n  = bx >> 5;
    const int y0 = (bx & 31) << 1;      // 2 output rows per block

    // ---- Phase A: x -> nibble-pair bytes in staging (256 threads) ----
    if (t < 256) {
        const int sy = t >> 6;          // strip row 0..3
        const int pr = t & 63;          // ci pair
        const int y  = y0 + sy - 1;
        uint32_t* sp = (uint32_t*)(Stg + sy * STG_SY + pr * 68);
        if (y >= 0 && y < HH) {
            const uint4* r0 =
                (const uint4*)(x + (((size_t)n * CIN + 2 * pr)     * HH + y) * WW);
            const uint4* r1 =
                (const uint4*)(x + (((size_t)n * CIN + 2 * pr + 1) * HH + y) * WW);
#pragma unroll
            for (int q = 0; q < 16; ++q) {
                const uint4 a = r0[q], b = r1[q];
                // byte i = fp4(even ci) | fp4(odd ci)<<4 ; 1.0f has bits 28,29 set
                uint32_t wd = ((a.x >> 28) & 0x2u)        | ((b.x >> 24) & 0x20u)
                            | ((a.y >> 20) & 0x200u)      | ((b.y >> 16) & 0x2000u)
                            | ((a.z >> 12) & 0x20000u)    | ((b.z >> 8) & 0x200000u)
                            | ((a.w >> 4)  & 0x2000000u)  | ( b.w       & 0x20000000u);
                sp[q] = wd;
            }
        } else {
#pragma unroll
            for (int q = 0; q < 16; ++q) sp[q] = 0u;
        }
    }
    __syncthreads();

    // ---- Phase B: transpose -> swizzled fp4 pixel blocks (264 threads) ----
    if (t < 264) {
        const int sy  = t / 66;
        const int pxp = t - sy * 66;    // padded pixel 0..65
        int8_t* dst = X4 + sy * X4ROW + pxp * 64;
        if (pxp == 0 || pxp == 65) {
            const int4 z = {0, 0, 0, 0};
#pragma unroll
            for (int c = 0; c < 4; ++c) *(int4*)(dst + c * 16) = z;
        } else {
            const int8_t* src = Stg + sy * STG_SY + (pxp - 1);
            uint32_t wrd[16];
#pragma unroll
            for (int k = 0; k < 16; ++k) {
                const uint32_t b0 = (uint8_t)src[(4 * k + 0) * 68];
                const uint32_t b1 = (uint8_t)src[(4 * k + 1) * 68];
                const uint32_t b2 = (uint8_t)src[(4 * k + 2) * 68];
                const uint32_t b3 = (uint8_t)src[(4 * k + 3) * 68];
                wrd[k] = b0 | (b1 << 8) | (b2 << 16) | (b3 << 24);
            }
            const int sk = pxp & 3;     // chunk swizzle key (verified pattern)
#pragma unroll
            for (int c = 0; c < 4; ++c) {
                int4 vv = {(int)wrd[c*4], (int)wrd[c*4+1],
                           (int)wrd[c*4+2], (int)wrd[c*4+3]};
                *(int4*)(dst + ((c ^ sk) << 4)) = vv;
            }
        }
    }
    __syncthreads();

    // ---- Phase C: GEMM (verified R11/R12 structure) ----
    const int wid  = t >> 6;            // 0..7
    const int lane = t & 63;
    const int m_lo = lane & 31;         // D col (m); A co row
    const int hi   = lane >> 5;         // k-half
    const int co_off = (wid >> 1) * 64; // 0,64,128,192
    const int yw     = wid & 1;         // output row y0 / y0+1
    const int ct0    = co_off >> 5;     // first co32 tile

    const int8_t* Xw  = X4 + yw * X4ROW;
    const int8_t* wqb = wq4 + lane * 16;

    v16f acc[2][2] = {};                // [ct][mt], fp32 exact

#pragma unroll
    for (int tap = 0; tap < 9; ++tap) {
        const int ky = tap / 3, kx = tap % 3;
        const int8_t* xl = Xw + ky * X4ROW;
        const int px0 = m_lo + kx;
        const int pk  = px0 & 3;

        v4i af[2][2];                   // [ct][s]
#pragma unroll
        for (int c = 0; c < 2; ++c)
#pragma unroll
            for (int s = 0; s < 2; ++s)
                af[c][s] = *(const v4i*)(wqb
                    + ((((tap * 8 + ct0 + c) * 2) + s) << 10));

        v4i bf[2][2];                   // [mt][s]
#pragma unroll
        for (int s = 0; s < 2; ++s) {
            const int sw = (((s << 1) + hi) ^ pk) << 4;
#pragma unroll
            for (int m = 0; m < 2; ++m)
                bf[m][s] = *(const v4i*)(xl + (px0 + m * 32) * 64 + sw);
        }
#pragma unroll
        for (int s = 0; s < 2; ++s)
#pragma unroll
            for (int c = 0; c < 2; ++c)
#pragma unroll
                for (int m = 0; m < 2; ++m)
                    acc[c][m] = __builtin_amdgcn_mfma_scale_f32_32x32x64_f8f6f4(
                        widen(af[c][s]), widen(bf[m][s]), acc[c][m],
                        4, 4,             // cbsz=fp4, blgp=fp4
                        0, 0x7F7F7F7F,    // scale_a = 2^0
                        0, 0x7F7F7F7F);   // scale_b = 2^0
    }

    // ---- epilogue: direct NT dword stores from acc (no LDS round-trip).
    // D 32x32 layout: col(m) = lane&31, row(co) = (r&3)+8*(r>>2)+4*hi.
    const float* bco = bias + co_off;
    const float* sco = sign + co_off;
    float* outb = out + ((size_t)n * COUT + co_off) * (HH * WW)
                + (y0 + yw) * WW + m_lo;
#pragma unroll
    for (int c = 0; c < 2; ++c) {
#pragma unroll
        for (int r = 0; r < 16; ++r) {
            const int co_l = c * 32 + (r & 3) + 8 * (r >> 2) + 4 * hi;
            const float bv = bco[co_l];
            const float sv = sco[co_l];
            float* orow = outb + (size_t)co_l * (HH * WW);
#pragma unroll
            for (int m = 0; m < 2; ++m) {
                const float yv = acc[c][m][r] + bv;     // exact integer
                const bool on = (sv > 0.0f) ? (yv >= 0.0f) : (yv <= 0.0f);
                __builtin_nontemporal_store(on ? 1.0f : 0.0f, orow + m * 32);
            }
        }
    }
}

// -------------------------------------------------------------------------
// Fallback (only if ws too small): naive direct conv.
__global__ __launch_bounds__(256) void naive_conv(
    const float* __restrict__ x, const float* __restrict__ w,
    const float* __restrict__ bias, const float* __restrict__ sign,
    float* __restrict__ out) {
    const int idx = blockIdx.x * 256 + threadIdx.x;
    const int xc = idx & 63, y = (idx >> 6) & 63, co = (idx >> 12) & 255,
              n = idx >> 20;
    float s = 0.f;
    for (int ci = 0; ci < CIN; ++ci)
        for (int ky = 0; ky < 3; ++ky) {
            const int iy = y + ky - 1;
            if (iy < 0 || iy >= HH) continue;
            for (int kx = 0; kx < 3; ++kx) {
                const int ix = xc + kx - 1;
                if (ix < 0 || ix >= WW) continue;
                s += x[((size_t)(n * CIN + ci) * HH + iy) * WW + ix] *
                     w[((size_t)(co * CIN + ci) * 3 + ky) * 3 + kx];
            }
        }
    const float yv = s + bias[co];
    out[idx] = ((sign[co] > 0.f) ? (yv >= 0.f) : (yv <= 0.f)) ? 1.0f : 0.0f;
}

// -------------------------------------------------------------------------
extern "C" void kernel_launch(void* const* d_in, const int* in_sizes, int n_in,
                              void* d_out, int out_size, void* d_ws, size_t ws_size,
                              hipStream_t stream) {
    const float* x    = (const float*)d_in[0];
    const float* w    = (const float*)d_in[1];
    const float* bias = (const float*)d_in[2];
    const float* sign = (const float*)d_in[3];
    float* out = (float*)d_out;

    if (ws_size < WQ4_BYTES) {
        naive_conv<<<dim3((NIMG * COUT * HH * WW) / 256), 256, 0, stream>>>(
            x, w, bias, sign, out);
        return;
    }
    int8_t* wq4 = (int8_t*)d_ws;

    w_prepack<<<dim3((int)((WQ4_BYTES + 255) / 256)), 256, 0, stream>>>(w, wq4);
    binconv_fused<<<dim3(NIMG * (HH / 2)), 512, 0, stream>>>(
        x, wq4, bias, sign, out);
}